// Round 4
// baseline (190.326 us; speedup 1.0000x reference)
//
#include <hip/hip_runtime.h>
#include <stdint.h>

// 3x3 conv s1 p1, NCHW fp32, 64->128ch, 16x112x112.
// R4: barrier-free implicit GEMM + occupancy fix.
//  prep: x -> zero-padded NHWC bf16 xt[n][114][114][64] via LDS transpose (coalesced both
//        sides); border zeroed by dedicated blocks; w -> Wt[tap][oc][ic] bf16.
//  conv: block = 128oc x 1 output row (112 px). 3-row x 114-col halo (43.8KB) DMA'd to LDS
//        once (global_load_lds w=16, XOR-swizzled chunks), ONE barrier, 9 taps x 252 MFMA
//        per wave, A-frags global->VGPR (L2-hot). 3 blocks/CU = 12 waves/CU.

#define HW      112
#define PIX     12544
#define ICN     64
#define OCN     128
#define PADW    114
#define PADPIX  12996          // 114*114
#define NIMG    16

#define XT_BYTES  (NIMG * PADPIX * ICN * 2)   // 26,615,808
#define WT_OFF    XT_BYTES                    // + 147,456 weight bytes
#define PXB       49                          // 12544/256 pixel-spans per image
#define XBLK      (NIMG * PXB)                // 784 transpose blocks
#define ZBLK      226                         // 16*452*8/256 border-zero blocks
#define WBLK      72
#define CONV_BLK  (NIMG * HW)                 // 1792

typedef __attribute__((ext_vector_type(8))) __bf16 bf16x8;
typedef __attribute__((ext_vector_type(4))) float  f32x4;

__device__ __forceinline__ uint32_t rne_lo(float f) {
    uint32_t u = __builtin_bit_cast(uint32_t, f);
    return (u + 0x7fffu + ((u >> 16) & 1u)) >> 16;
}
__device__ __forceinline__ uint32_t pk2(float a, float b) {
    uint32_t ub = __builtin_bit_cast(uint32_t, b);
    ub = (ub + 0x7fffu + ((ub >> 16) & 1u)) & 0xffff0000u;
    return rne_lo(a) | ub;
}
__device__ __forceinline__ void load_lds16(const void* g, void* l) {
    __builtin_amdgcn_global_load_lds(
        (const __attribute__((address_space(1))) uint32_t*)g,
        (__attribute__((address_space(3))) uint32_t*)l, 16, 0, 0);
}

// ---------------- prep ----------------
__global__ void __launch_bounds__(256)
prep(const float* __restrict__ x, const float* __restrict__ w, uint8_t* __restrict__ ws) {
    __shared__ uint32_t S[256 * 33];   // [px][icpair], +1 dword pad per row
    const int b = blockIdx.x;
    const int t = threadIdx.x;

    if (b < XBLK) {
        // ---- transpose 256 px x 64 ic, both global sides coalesced
        const int n  = b / PXB;
        const int p0 = (b - n * PXB) * 256;
        const float* src = x + (size_t)n * ICN * PIX + p0 + t;
#pragma unroll
        for (int j = 0; j < 32; ++j) {
            float f0 = src[(size_t)(2 * j) * PIX];
            float f1 = src[(size_t)(2 * j + 1) * PIX];
            S[t * 33 + j] = pk2(f0, f1);
        }
        __syncthreads();
#pragma unroll
        for (int wv = 0; wv < 8; ++wv) {
            const int c   = wv * 256 + t;    // 0..2047 : 256 px x 8 chunks
            const int pxl = c >> 3;
            const int icc = c & 7;
            const uint32_t* sp = &S[pxl * 33 + icc * 4];
            uint4 v = make_uint4(sp[0], sp[1], sp[2], sp[3]);
            const int px = p0 + pxl;
            const int h  = px / HW;
            const int wd = px - h * HW;
            char* dst = (char*)ws +
                ((size_t)(n * PADPIX + (h + 1) * PADW + wd + 1)) * 128 + icc * 16;
            *(uint4*)dst = v;
        }
    } else if (b < XBLK + ZBLK) {
        // ---- zero the padded border (452 px/img * 8 chunks * 16 img = 57856 chunks)
        const int g    = (b - XBLK) * 256 + t;
        const int img  = g / 3616;
        const int rem  = g - img * 3616;
        const int pxi  = rem >> 3;
        const int icc  = rem & 7;
        int hp, wp;
        if (pxi < PADW)            { hp = 0;   wp = pxi; }
        else if (pxi < 2 * PADW)   { hp = 113; wp = pxi - PADW; }
        else { int j = pxi - 2 * PADW; hp = 1 + (j >> 1); wp = (j & 1) * 113; }
        char* dst = (char*)ws + ((size_t)(img * PADPIX + hp * PADW + wp)) * 128 + icc * 16;
        *(uint4*)dst = make_uint4(0, 0, 0, 0);
    } else {
        // ---- weights: Wt[tap][oc][ic] bf16
        uint16_t* wt = (uint16_t*)(ws + WT_OFF);
        const int wb = b - XBLK - ZBLK;
#pragma unroll
        for (int k = 0; k < 4; ++k) {
            int wi = wb * 1024 + k * 256 + t;           // [0, 73728)
            int r  = wi >> 13;
            int oc = (wi >> 6) & 127;
            int ic = wi & 63;
            wt[wi] = (uint16_t)rne_lo(w[oc * 576 + ic * 9 + r]);
        }
    }
}

// ---------------- conv ----------------
__global__ void __launch_bounds__(256, 3)
conv_mfma(const uint8_t* __restrict__ ws, const float* __restrict__ bias,
          float* __restrict__ out) {
    __shared__ uint8_t Xs[3 * PADW * 128];   // 43,776 B halo: [hl 0..2][w' 0..113][64ic]

    const char* xt = (const char*)ws;
    const char* wt = (const char*)(ws + WT_OFF);

    const int t = threadIdx.x;
    const int b = blockIdx.x;
    const int n  = b / HW;
    const int oh = b - n * HW;                // output row

    const int lane = t & 63;
    const int wave = t >> 6;
    const int lr = lane & 15;
    const int lq = lane >> 4;
    const int oc_w = wave * 32;               // 4 waves x 32 oc, all px

    // ---- halo DMA: 3*114 px-rows x 8 chunks = 2736 16B chunks, one contiguous region.
    // LDS linear; global side fetches chunk (c ^ (r&7)) so readers un-swizzle.
    {
        const char* hbase = xt + ((size_t)(n * PADPIX + oh * PADW)) * 128;
#pragma unroll
        for (int i = 0; i < 10; ++i) {
            const int idx = i * 256 + t;
            const int r = idx >> 3, c = idx & 7;
            load_lds16(hbase + r * 128 + ((c ^ (r & 7)) * 16), (char*)Xs + idx * 16);
        }
        if (t < 176) {                         // tail chunks 2560..2735
            const int idx = 2560 + t;
            const int r = idx >> 3, c = idx & 7;
            load_lds16(hbase + r * 128 + ((c ^ (r & 7)) * 16), (char*)Xs + idx * 16);
        }
    }
    __syncthreads();   // only barrier in the kernel (drains DMA)

    f32x4 acc[2][7];
    {
        f32x4 z = {0.f, 0.f, 0.f, 0.f};
#pragma unroll
        for (int i = 0; i < 2; ++i)
#pragma unroll
            for (int j = 0; j < 7; ++j) acc[i][j] = z;
    }

    // per-lane weight base: A[m=lr -> oc][k chunk = kh*4+lq]
    const char* abase = wt + (oc_w + lr) * 128 + lq * 16;

#pragma unroll
    for (int tap = 0; tap < 9; ++tap) {
        const int dy = tap / 3 - 1;
        const int dx = tap - (tap / 3) * 3 - 1;
        // B px-row in halo: hl = dy+1 ; w' = ni*16 + lr + dx + 1
        const int r0 = (dy + 1) * PADW + dx + 1 + lr;
        const int r7 = r0 & 7;                 // invariant in ni (16 % 8 == 0)
        const int s0 = (lq ^ r7) * 16;
        const int s1 = s0 ^ 64;                // chunk lq+4
        const char* bbase = (const char*)Xs + r0 * 128;

        bf16x8 a0 = *(const bf16x8*)(abase + tap * 16384);
        bf16x8 a1 = *(const bf16x8*)(abase + tap * 16384 + 64);
        bf16x8 a2 = *(const bf16x8*)(abase + tap * 16384 + 2048);
        bf16x8 a3 = *(const bf16x8*)(abase + tap * 16384 + 2048 + 64);
#pragma unroll
        for (int ni = 0; ni < 7; ++ni) {
            bf16x8 b0 = *(const bf16x8*)(bbase + ni * 2048 + s0);
            bf16x8 b1 = *(const bf16x8*)(bbase + ni * 2048 + s1);
            acc[0][ni] = __builtin_amdgcn_mfma_f32_16x16x32_bf16(a0, b0, acc[0][ni], 0, 0, 0);
            acc[1][ni] = __builtin_amdgcn_mfma_f32_16x16x32_bf16(a2, b0, acc[1][ni], 0, 0, 0);
            acc[0][ni] = __builtin_amdgcn_mfma_f32_16x16x32_bf16(a1, b1, acc[0][ni], 0, 0, 0);
            acc[1][ni] = __builtin_amdgcn_mfma_f32_16x16x32_bf16(a3, b1, acc[1][ni], 0, 0, 0);
        }
    }

    // ---- epilogue: D col = lr -> pixel (ow = ni*16+lr), row = lq*4+rg -> oc
#pragma unroll
    for (int mi = 0; mi < 2; ++mi) {
#pragma unroll
        for (int rg = 0; rg < 4; ++rg) {
            const int oc = oc_w + mi * 16 + lq * 4 + rg;
            const float bb = bias[oc];
            float* orow = out + ((size_t)(n * OCN + oc)) * PIX + oh * HW + lr;
#pragma unroll
            for (int ni = 0; ni < 7; ++ni)
                orow[ni * 16] = acc[mi][ni][rg] + bb;
        }
    }
}

extern "C" void kernel_launch(void* const* d_in, const int* in_sizes, int n_in,
                              void* d_out, int out_size, void* d_ws, size_t ws_size,
                              hipStream_t stream) {
    const float* x    = (const float*)d_in[0];
    const float* w    = (const float*)d_in[1];
    const float* bias = (const float*)d_in[2];
    float* out = (float*)d_out;
    uint8_t* ws = (uint8_t*)d_ws;   // needs 26,763,264 bytes

    prep<<<XBLK + ZBLK + WBLK, 256, 0, stream>>>(x, w, ws);
    conv_mfma<<<CONV_BLK, 256, 0, stream>>>(ws, bias, out);
}